// Round 14
// baseline (171.674 us; speedup 1.0000x reference)
//
#include <hip/hip_runtime.h>
#include <math.h>

// GQA block. Round 17: GEMMs -> BK=64 (16 MFMA + 12 ds_read per barrier pair,
// the m97-ladder ratio) while keeping the BALANCED 128x64 grids (32x24=3.0/CU,
// 32x16=2.0/CU) that r16 proved out. 2-buf x 24KB = 48KB LDS -> still 3
// blocks/CU; 12 waves/CU hide the depth-1 prefetch (m97 precedent). Barrier
// count halves. Accumulation order unchanged -> bit-identical results.
// prep_all / attn byte-identical to r16 (168.4us, absmax 2.4e-4).
// Shapes: B=2, T=2048, DIM=1024, H=16, HKV=4, HD=64.

#define B_   2
#define T_   2048
#define DIM_ 1024
#define NH   16
#define NKV  4
#define HD_  64
#define BT_  (B_ * T_)

typedef _Float16 half8_t __attribute__((ext_vector_type(8)));
typedef _Float16 half4_t __attribute__((ext_vector_type(4)));
typedef float    f32x4   __attribute__((ext_vector_type(4)));

__device__ __forceinline__ void async_copy16(_Float16* lds, const _Float16* g) {
    __builtin_amdgcn_global_load_lds(
        (const __attribute__((address_space(1))) void*)g,
        (__attribute__((address_space(3))) void*)lds, 16, 0, 0);
}

#define VMCNT(n) asm volatile("s_waitcnt vmcnt(" #n ")" ::: "memory")
#define LGKMCNT0() asm volatile("s_waitcnt lgkmcnt(0)" ::: "memory")

__device__ __forceinline__ void wg_barrier() {
    asm volatile("" ::: "memory");
    __builtin_amdgcn_s_barrier();
    asm volatile("" ::: "memory");
}

// ---------------------------------------------------------------------------
// Kernel 1: fused prep, OUTPUT-LINEAR. Block ranges:
//   [0,256): tab; [256,1536): W -> fp16 chunks (single plane);
//   [1536,3584): A chunks.
// Chunk idx bits: l15[0:3] k8[4:5] u7[6:8] kb[9:13] nb[14:]; holds
// X[nb*128 + u7*16 + l15][kb*32 + k8*8 .. +8].
// ---------------------------------------------------------------------------
__global__ __launch_bounds__(256) void prep_all_kernel(
    float2* __restrict__ tab,
    const float* __restrict__ Wq, const float* __restrict__ Wk,
    const float* __restrict__ Wv, const float* __restrict__ Wo,
    _Float16* __restrict__ Whi,
    const float* __restrict__ hs, _Float16* __restrict__ Ah)
{
    const int bid = blockIdx.x;
    const int tid = threadIdx.x;
    if (bid < 256) {
        int gid = bid * 256 + tid;                // 0..65535
        int t = gid >> 5, i = gid & 31;
        double invf = pow(10000.0, -(double)i / 32.0);
        double ang  = (double)t * invf;
        tab[gid] = make_float2((float)cos(ang), (float)sin(ang));
    } else if (bid < 1536) {
        int idx = (bid - 256) * 256 + tid;        // 0..327679 output chunk
        int l15 = idx & 15, k8 = (idx >> 4) & 3, u7 = (idx >> 6) & 7;
        int kb = (idx >> 9) & 31, nb = idx >> 14;
        int n = nb * 128 + u7 * 16 + l15, k = kb * 32 + k8 * 8;
        const float* src;
        if (n < 1024)      src = Wq + (size_t)n * 1024;
        else if (n < 1280) src = Wk + (size_t)(n - 1024) * 1024;
        else if (n < 1536) src = Wv + (size_t)(n - 1280) * 1024;
        else               src = Wo + (size_t)(n - 1536) * 1024;
        float4 f0 = *(const float4*)(src + k);
        float4 f1 = *(const float4*)(src + k + 4);
        half8_t hi;
        hi[0] = (_Float16)f0.x; hi[1] = (_Float16)f0.y;
        hi[2] = (_Float16)f0.z; hi[3] = (_Float16)f0.w;
        hi[4] = (_Float16)f1.x; hi[5] = (_Float16)f1.y;
        hi[6] = (_Float16)f1.z; hi[7] = (_Float16)f1.w;
        *(half8_t*)&Whi[(size_t)idx * 8] = hi;
    } else {
        int idx = (bid - 1536) * 256 + tid;       // 0..524287 output chunk
        int l15 = idx & 15, k8 = (idx >> 4) & 3, u7 = (idx >> 6) & 7;
        int kb = (idx >> 9) & 31, mb = idx >> 14;
        const float* src = hs + (size_t)(mb * 128 + u7 * 16 + l15) * 1024
                              + kb * 32 + k8 * 8;
        float4 f0 = *(const float4*)src;
        float4 f1 = *(const float4*)(src + 4);
        half8_t hv;
        hv[0] = (_Float16)f0.x; hv[1] = (_Float16)f0.y;
        hv[2] = (_Float16)f0.z; hv[3] = (_Float16)f0.w;
        hv[4] = (_Float16)f1.x; hv[5] = (_Float16)f1.y;
        hv[6] = (_Float16)f1.z; hv[7] = (_Float16)f1.w;
        *(half8_t*)&Ah[(size_t)idx * 8] = hv;
    }
}

// ---------------------------------------------------------------------------
// Kernel 3: single-plane MFMA GEMM, all-DMA staging. C = A @ Whi^T + bias.
// 128x64 tile, BK=64 (2 kb units/step), 2-buf depth-1 (vmcnt(6)), 4 waves
// as 2x2. Per step: 16 MFMA, 12 ds_read_b128, 6 DMA/thread, 2 barriers.
// 48KB LDS -> 3 blocks/CU. Grid x=mb (W-panel L2 reuse); grids balanced.
// MODE 0: fused epilogue -- q/k: LDS-staged rope -> fp16 qh/kh;
//         v: direct interleaved vth stores.  MODE 1: row-major fp32 + bias.
// ---------------------------------------------------------------------------
template <int MODE>
__global__ __launch_bounds__(256, 3) void gemm2p_kernel(
    const _Float16* __restrict__ Ah,
    const _Float16* __restrict__ Whi,
    int nj0,
    const float* __restrict__ bq, const float* __restrict__ bk,
    const float* __restrict__ bv,
    const float2* __restrict__ tab,
    float* __restrict__ o0f,
    _Float16* __restrict__ qh, _Float16* __restrict__ kh,
    _Float16* __restrict__ vth)
{
    // 48KB: 2 bufs (sA 16K each | sBh 8K each); MODE0 epilogue reuses the
    // first 32KB as a 128x64 fp32 tile.
    __shared__ __align__(16) char smem[49152];
    _Float16 (*sA )[8192] = (_Float16(*)[8192])(smem);           // 2 x 16KB
    _Float16 (*sBh)[4096] = (_Float16(*)[4096])(smem + 32768);   // 2 x 8KB

    const int tid  = threadIdx.x;
    const int w    = tid >> 6, lane = tid & 63;
    const int quad = lane >> 4, l15 = lane & 15;
    const int wm = w >> 1, wn = w & 1;
    const int mb   = blockIdx.x;          // x = row tile (W-panel L2 reuse)
    const int nblk = blockIdx.y;
    const int nj   = nj0 + nblk;

    const _Float16* AB = Ah + (size_t)mb * 32 * 4096;
    const size_t woff = (size_t)(nj >> 1) * 32 * 4096 + (size_t)(nj & 1) * 2048;
    const _Float16* WhiB = Whi + woff;

    f32x4 acc[4][2];
#pragma unroll
    for (int mt = 0; mt < 4; ++mt)
#pragma unroll
        for (int nt = 0; nt < 2; ++nt) {
            f32x4 z = {0.f, 0.f, 0.f, 0.f};
            acc[mt][nt] = z;
        }

    // Stage kb-pair (2*kbl, 2*kbl+1): A 1024 chunks (4/thread), B 2x256
    // chunks (2/thread). B slices are 2048-half windows of the 4096 W units.
#define GEMM_STAGE(buf, kbl)                                                  \
    {                                                                         \
        const _Float16* ga  = AB   + (size_t)(kbl) * 8192;                    \
        const _Float16* gh0 = WhiB + (size_t)(2 * (kbl))     * 4096;          \
        const _Float16* gh1 = WhiB + (size_t)(2 * (kbl) + 1) * 4096;          \
        int cb = w * 64;                                                      \
        async_copy16(&sA [buf][(cb)       * 8], ga  + (size_t)(cb + lane)       * 8); \
        async_copy16(&sA [buf][(cb + 256) * 8], ga  + (size_t)(cb + 256 + lane) * 8); \
        async_copy16(&sA [buf][(cb + 512) * 8], ga  + (size_t)(cb + 512 + lane) * 8); \
        async_copy16(&sA [buf][(cb + 768) * 8], ga  + (size_t)(cb + 768 + lane) * 8); \
        async_copy16(&sBh[buf][(cb)       * 8], gh0 + (size_t)(cb + lane)       * 8); \
        async_copy16(&sBh[buf][(cb + 256) * 8], gh1 + (size_t)(cb + lane)       * 8); \
    }

    GEMM_STAGE(0, 0);

    for (int kb = 0; kb < 16; ++kb) {
        const int cur = kb & 1;
        if (kb + 1 < 16) {
            GEMM_STAGE(cur ^ 1, kb + 1);
            VMCNT(6);           // stage(kb) done; stage(kb+1) in flight
        } else {
            VMCNT(0);
        }
        wg_barrier();

        half8_t af[2][4], bf[2][2];
#pragma unroll
        for (int kk = 0; kk < 2; ++kk) {
#pragma unroll
            for (int mt = 0; mt < 4; ++mt)
                af[kk][mt] = *(const half8_t*)&sA[cur][kk * 4096 + (((wm * 4 + mt) * 64) + lane) * 8];
#pragma unroll
            for (int nt = 0; nt < 2; ++nt)
                bf[kk][nt] = *(const half8_t*)&sBh[cur][kk * 2048 + (((wn * 2 + nt) * 64) + lane) * 8];
        }
#pragma unroll
        for (int kk = 0; kk < 2; ++kk)
#pragma unroll
            for (int mt = 0; mt < 4; ++mt)
#pragma unroll
                for (int nt = 0; nt < 2; ++nt)
                    acc[mt][nt] = __builtin_amdgcn_mfma_f32_16x16x32_f16(
                        af[kk][mt], bf[kk][nt], acc[mt][nt], 0, 0, 0);
        LGKMCNT0();             // LDS reads of buf[cur] retired
        wg_barrier();           // safe for stage(kb+2) to overwrite buf[cur]
    }

    if constexpr (MODE == 0) {
        // kind: 0=q (rope, scale), 1=k (rope), 2=v (direct interleave)
        const float* bias; int hh, kind;
        if (nj < 16)      { bias = bq; hh = nj;      kind = 0; }
        else if (nj < 20) { bias = bk; hh = nj - 16; kind = 1; }
        else              { bias = bv; hh = nj - 20; kind = 2; }
        const int b_ = mb >> 4;
        float bias2[2];
#pragma unroll
        for (int nt = 0; nt < 2; ++nt)
            bias2[nt] = bias[hh * 64 + wn * 32 + nt * 16 + l15];

        if (kind == 2) {
            // lane (quad,l15), mt-pair j: one vth unit per (j,nt):
            // u = 2*wm+j, dt = 2*wn+nt, keys {32u+4quad+r, +16+r} = acc rows.
            const int bhk = b_ * NKV + hh;
            const int kt2 = mb & 15;
            _Float16* base = vth + (size_t)(bhk * 16 + kt2) * 1024 * 8;
#pragma unroll
            for (int j = 0; j < 2; ++j)
#pragma unroll
                for (int nt = 0; nt < 2; ++nt) {
                    int u = wm * 2 + j, dt = wn * 2 + nt;
                    half8_t hv;
#pragma unroll
                    for (int r = 0; r < 4; ++r) {
                        hv[r]     = (_Float16)(acc[2 * j][nt][r]     + bias2[nt]);
                        hv[4 + r] = (_Float16)(acc[2 * j + 1][nt][r] + bias2[nt]);
                    }
                    int c = u * 256 + dt * 64 + quad * 16 + l15;
                    *(half8_t*)(base + (size_t)c * 8) = hv;
                }
        } else {
            // stage 128x64 fp32 tile (swizzled: col ^ ((row>>2)&7)<<2)
            float* tile = (float*)smem;
#pragma unroll
            for (int mt = 0; mt < 4; ++mt)
#pragma unroll
                for (int nt = 0; nt < 2; ++nt)
#pragma unroll
                    for (int r = 0; r < 4; ++r) {
                        int rr  = wm * 64 + mt * 16 + quad * 4 + r;
                        int col = wn * 32 + nt * 16 + l15;
                        int sc_ = col ^ (((rr >> 2) & 7) << 2);
                        tile[rr * 64 + sc_] = acc[mt][nt][r] + bias2[nt];
                    }
            __syncthreads();
            // rope: thread = (row rr, half ih); i = 16*ih + ii, ii=0..15
            const int rr = tid >> 1, ih = tid & 1;
            const int t_ = (mb & 15) * 128 + rr;
            const int swz = ((rr >> 2) & 7) << 2;
            const float* trow = tile + rr * 64;
            const float sc = (kind == 0) ? 0.125f : 1.0f;
            _Float16* dst = ((kind == 0) ? qh : kh) +
                ((size_t)(b_ * ((kind == 0) ? NH : NKV) + hh) * T_ + t_) * 64;
            half8_t lo0, lo1, hi0, hi1;
#pragma unroll
            for (int ii = 0; ii < 16; ++ii) {
                int i = ih * 16 + ii;
                float2 cs = tab[t_ * 32 + i];
                float x0 = trow[i ^ swz];
                float x1 = trow[(i + 32) ^ swz];
                float xe = trow[(2 * i) ^ swz];
                float xo = trow[(2 * i + 1) ^ swz];
                float olo = (x0 * cs.x - xo * cs.y) * sc;
                float ohi = (x1 * cs.x + xe * cs.y) * sc;
                if (ii < 8) { lo0[ii] = (_Float16)olo; hi0[ii] = (_Float16)ohi; }
                else        { lo1[ii - 8] = (_Float16)olo; hi1[ii - 8] = (_Float16)ohi; }
            }
            *(half8_t*)(dst + ih * 16)          = lo0;
            *(half8_t*)(dst + ih * 16 + 8)      = lo1;
            *(half8_t*)(dst + 32 + ih * 16)     = hi0;
            *(half8_t*)(dst + 32 + ih * 16 + 8) = hi1;
        }
    } else {
        const int m0 = mb * 128;
        int n0 = nblk * 64 + wn * 32;
#pragma unroll
        for (int mt = 0; mt < 4; ++mt)
#pragma unroll
            for (int r = 0; r < 4; ++r) {
                int m = m0 + wm * 64 + mt * 16 + quad * 4 + r;
#pragma unroll
                for (int nt = 0; nt < 2; ++nt) {
                    int n = n0 + nt * 16 + l15;
                    o0f[(size_t)m * 1024 + n] = acc[mt][nt][r] + bq[n];
                }
            }
    }
#undef GEMM_STAGE
}

// ---------------------------------------------------------------------------
// Kernel 6: flash attention, 128 q/block, 32 q/wave, KVBLK=128, PV K=32
// (50.5us, 0 conflicts). Byte-identical to r16.
// ---------------------------------------------------------------------------
__global__ __launch_bounds__(256, 2) void attn_kernel(
    const _Float16* __restrict__ qh, const _Float16* __restrict__ kh,
    const _Float16* __restrict__ vth, _Float16* __restrict__ ctx_h)
{
    __shared__ _Float16 Ks[2][8192];
    __shared__ _Float16 Vs[2][8192];

    const int qt = blockIdx.x;          // 0..15 (128-q tiles)
    const int bh = blockIdx.y;          // 0..31
    const int b  = bh >> 4, h = bh & 15, hk = h >> 2;
    const int tid  = threadIdx.x;
    const int w    = tid >> 6;
    const int lane = tid & 63;
    const int quad = lane >> 4, l15 = lane & 15;

    // Q B-frags for 2 strips of 16 q-rows (q pre-scaled by 0.125 at rope)
    half8_t aq0[2], aq1[2];
#pragma unroll
    for (int s = 0; s < 2; ++s) {
        const _Float16* Qb = qh +
            ((size_t)(b * NH + h) * T_ + qt * 128 + w * 32 + s * 16 + l15) * 64 + quad * 8;
        aq0[s] = *(const half8_t*)(Qb);
        aq1[s] = *(const half8_t*)(Qb + 32);
    }
    // Force Q loads resolved here -> no compiler vmcnt waits inside the loop.
    asm volatile("" :: "v"(aq0[0]), "v"(aq0[1]), "v"(aq1[0]), "v"(aq1[1]));

    const _Float16* Kb = kh  + (size_t)(b * NKV + hk) * (T_ * 64);
    const _Float16* Vb = vth + (size_t)(b * NKV + hk) * (64 * T_);

    // Stage one 128-key tile-pair: K 1024 chunks + V 1024 chunks, 8 DMA/thread.
#define ATTN_STAGE(buf, ktile)                                                \
    {                                                                         \
        _Float16* kd = &Ks[buf][0];                                           \
        _Float16* vd = &Vs[buf][0];                                           \
        _Pragma("unroll")                                                     \
        for (int p = 0; p < 4; ++p) {                                         \
            int cb = p * 256 + w * 64;                                        \
            int c  = cb + lane;                                               \
            int kl = c & 15, kq = (c >> 4) & 3, ktt = (c >> 6) & 7, kr = c >> 9; \
            const _Float16* kg = Kb + ((size_t)((ktile) * 128 + ktt * 16 + kl)) * 64 + (kr * 4 + kq) * 8; \
            const _Float16* vg = Vb + ((size_t)(ktile) * 1024 + c) * 8;       \
            async_copy16(kd + cb * 8, kg);                                    \
            async_copy16(vd + cb * 8, vg);                                    \
        }                                                                     \
    }

    float l_i[2] = {0.0f, 0.0f};
    f32x4 o_acc[2][4];
#pragma unroll
    for (int s = 0; s < 2; ++s)
#pragma unroll
        for (int dt = 0; dt < 4; ++dt) { f32x4 z = {0.f,0.f,0.f,0.f}; o_acc[s][dt] = z; }

    ATTN_STAGE(0, 0);

    for (int kt = 0; kt < T_ / 128; ++kt) {
        const int cur = kt & 1;
        if (kt + 1 < T_ / 128) {
            ATTN_STAGE(cur ^ 1, kt + 1);
            VMCNT(8);           // wait stage(cur) only; stage(next) in flight
        } else {
            VMCNT(0);
        }
        wg_barrier();           // buf[cur] ready across all waves

#pragma unroll
        for (int u = 0; u < 4; ++u) {
            // K frags for t=2u, 2u+1: wave-contiguous 1KiB b128 reads
            half8_t ak0[2], ak1[2];
#pragma unroll
            for (int tt = 0; tt < 2; ++tt) {
                const _Float16* kr_ = &Ks[cur][((2 * u + tt) * 64 + lane) * 8];
                ak0[tt] = *(const half8_t*)(kr_);
                ak1[tt] = *(const half8_t*)(kr_ + 4096);
            }
            // V A-frags (16x16x32): av8[dt][j] = V^T[d=16dt+l15][K(quad,j)]
            // with K(q,j) = 32u+4q+j (j<4) / 32u+16+4q+j-4 (j>=4).
            half8_t av8[4];
#pragma unroll
            for (int dt = 0; dt < 4; ++dt)
                av8[dt] = *(const half8_t*)&Vs[cur][((u * 4 + dt) * 64 + lane) * 8];

#pragma unroll
            for (int s = 0; s < 2; ++s) {
                // S^T for both 16-key halves of the 32-key u-group
                f32x4 z0 = {0.f,0.f,0.f,0.f}, z1 = {0.f,0.f,0.f,0.f};
                z0 = __builtin_amdgcn_mfma_f32_16x16x32_f16(ak0[0], aq0[s], z0, 0, 0, 0);
                f32x4 sv0 = __builtin_amdgcn_mfma_f32_16x16x32_f16(ak1[0], aq1[s], z0, 0, 0, 0);
                z1 = __builtin_amdgcn_mfma_f32_16x16x32_f16(ak0[1], aq0[s], z1, 0, 0, 0);
                f32x4 sv1 = __builtin_amdgcn_mfma_f32_16x16x32_f16(ak1[1], aq1[s], z1, 0, 0, 0);
                // P: lane (quad,l15) elem j holds exactly P[K(quad,j)][q=l15]
                float p0 = __expf(sv0[0]), p1 = __expf(sv0[1]);
                float p2 = __expf(sv0[2]), p3 = __expf(sv0[3]);
                float p4 = __expf(sv1[0]), p5 = __expf(sv1[1]);
                float p6 = __expf(sv1[2]), p7 = __expf(sv1[3]);
                l_i[s] += ((p0 + p1) + (p2 + p3)) + ((p4 + p5) + (p6 + p7));
                half8_t pb8;
                pb8[0] = (_Float16)p0; pb8[1] = (_Float16)p1;
                pb8[2] = (_Float16)p2; pb8[3] = (_Float16)p3;
                pb8[4] = (_Float16)p4; pb8[5] = (_Float16)p5;
                pb8[6] = (_Float16)p6; pb8[7] = (_Float16)p7;
#pragma unroll
                for (int dt = 0; dt < 4; ++dt)
                    o_acc[s][dt] = __builtin_amdgcn_mfma_f32_16x16x32_f16(
                        av8[dt], pb8, o_acc[s][dt], 0, 0, 0);
            }
        }
        LGKMCNT0();             // all LDS reads of buf[cur] retired
        wg_barrier();           // safe for next iter's DMA to overwrite
    }

    // epilogue: reduce l across quads, normalize, packed half4 ctx stores.
    const int mb = b * 16 + qt;
#pragma unroll
    for (int s = 0; s < 2; ++s) {
        float l = l_i[s];
        l += __shfl_xor(l, 16);
        l += __shfl_xor(l, 32);
        float inv = 1.0f / l;
#pragma unroll
        for (int dt = 0; dt < 4; ++dt) {
            int kb_ = 2 * h + (dt >> 1);
            int k8  = (2 * dt + (quad >> 1)) & 3;
            size_t idx = (size_t)(mb * 32 + kb_) * 512 + (w * 2 + s) * 64 + k8 * 16 + l15;
            half4_t hv;
#pragma unroll
            for (int r = 0; r < 4; ++r)
                hv[r] = (_Float16)(o_acc[s][dt][r] * inv);
            *(half4_t*)&ctx_h[idx * 8 + 4 * (quad & 1)] = hv;
        }
    }
#undef ATTN_STAGE
}

// ---------------------------------------------------------------------------
extern "C" void kernel_launch(void* const* d_in, const int* in_sizes, int n_in,
                              void* d_out, int out_size, void* d_ws, size_t ws_size,
                              hipStream_t stream)
{
    const float* hs = (const float*)d_in[0];
    const float* Wq = (const float*)d_in[1];
    const float* bq = (const float*)d_in[2];
    const float* Wk = (const float*)d_in[3];
    const float* bk = (const float*)d_in[4];
    const float* Wv = (const float*)d_in[5];
    const float* bv = (const float*)d_in[6];
    const float* Wo = (const float*)d_in[7];
    const float* bo = (const float*)d_in[8];
    float* out = (float*)d_out;

    const size_t MB = 1024 * 1024;
    if (ws_size < 46 * MB) return;

    char* w = (char*)d_ws;
    _Float16* Whi  = (_Float16*)(w);              // 5 MB  [0,5)
    _Float16* hs_h = (_Float16*)(w + 5 * MB);     // 8 MB  [5,13) A chunks
    _Float16* qh   = (_Float16*)(w + 13 * MB);    // 8 MB  [13,21)
    _Float16* kh   = (_Float16*)(w + 21 * MB);    // 2 MB  [21,23)
    _Float16* vth  = (_Float16*)(w + 23 * MB);    // 2 MB  [23,25)
    float2*   tab  = (float2*)(w + 25 * MB);      // 0.5MB [25,25.5)
    // ctx aliases hs_h: A chunks dead once gemm<0> completes; attn (which
    // writes ctx) runs strictly after.
    _Float16* ctx_h = hs_h;

    prep_all_kernel<<<3584, 256, 0, stream>>>(
        tab, Wq, Wk, Wv, Wo, Whi, hs, hs_h);
    gemm2p_kernel<0><<<dim3(32, 24), 256, 0, stream>>>(
        hs_h, Whi, 0, bq, bk, bv, tab, nullptr, qh, kh, vth);
    attn_kernel<<<dim3(T_ / 128, B_ * NH), 256, 0, stream>>>(qh, kh, vth, ctx_h);
    gemm2p_kernel<1><<<dim3(32, 16), 256, 0, stream>>>(
        ctx_h, Whi, 24, bo, nullptr, nullptr, tab, out, nullptr, nullptr, nullptr);
}